// Round 1
// baseline (560.474 us; speedup 1.0000x reference)
//
#include <hip/hip_runtime.h>
#include <hip/hip_bf16.h>
#include <cstdint>

#define NB 4
#define TT 2048
#define DM 1024
#define NH 16
#define HD 64

typedef __attribute__((ext_vector_type(8))) short bf16x8;
typedef __attribute__((ext_vector_type(4))) float f32x4;
typedef __attribute__((ext_vector_type(4))) float float4v;

static __device__ __forceinline__ unsigned short f2bf(float x) {
    unsigned int u = __float_as_uint(x);
    unsigned int r = (u + 0x7fffu + ((u >> 16) & 1u)) >> 16;
    return (unsigned short)r;
}

// ---- W[k][n] f32 -> Wt[n][k] bf16 (transpose + convert) ----
__global__ __launch_bounds__(256) void k_transpose_w(const float* __restrict__ W,
                                                     unsigned short* __restrict__ Wt) {
    __shared__ unsigned short tile[32][33];
    int tx = threadIdx.x, ty = threadIdx.y;
    int kb = blockIdx.x * 32, nb = blockIdx.y * 32;
#pragma unroll
    for (int i = 0; i < 4; ++i)
        tile[ty + i * 8][tx] = f2bf(W[(size_t)(kb + ty + i * 8) * DM + nb + tx]);
    __syncthreads();
#pragma unroll
    for (int i = 0; i < 4; ++i)
        Wt[(size_t)(nb + ty + i * 8) * DM + kb + tx] = tile[tx][ty + i * 8];
}

// ---- GEMM: C[M=8192][1024] = A[M][1024] @ W[1024][1024] (+bias)*scale ----
// Bt is W transposed: Bt[n][k].  OUT_MODE 0: scatter bf16 to [b,h,t,d]; 1: f32 row-major.
template <int OUT_MODE, bool A_BF16>
__global__ __launch_bounds__(256) void k_gemm(const void* __restrict__ Av,
                                              const unsigned short* __restrict__ Bt,
                                              const float* __restrict__ bias,
                                              void* __restrict__ Cv, float scale) {
    __shared__ __align__(16) unsigned short As[128][56];
    __shared__ __align__(16) unsigned short Bs[128][56];
    const int tid = threadIdx.x;
    const int lane = tid & 63, wid = tid >> 6;
    const int lg = lane >> 4, lc = lane & 15;
    const int wm = wid >> 1, wn = wid & 1;
    const int m0 = blockIdx.x * 128, n0 = blockIdx.y * 128;

    f32x4 acc[4][4];
#pragma unroll
    for (int mi = 0; mi < 4; ++mi)
#pragma unroll
        for (int ni = 0; ni < 4; ++ni)
            acc[mi][ni] = (f32x4){0.f, 0.f, 0.f, 0.f};

    for (int k0 = 0; k0 < DM; k0 += 32) {
        __syncthreads();
        if (!A_BF16) {
            const float* A = (const float*)Av;
#pragma unroll
            for (int p = 0; p < 4; ++p) {
                int r = p * 32 + (tid >> 3);
                int cs = (tid & 7) * 4;
                float4v v = *(const float4v*)(A + (size_t)(m0 + r) * DM + k0 + cs);
                As[r][cs + 0] = f2bf(v[0]);
                As[r][cs + 1] = f2bf(v[1]);
                As[r][cs + 2] = f2bf(v[2]);
                As[r][cs + 3] = f2bf(v[3]);
            }
        } else {
            const unsigned short* A = (const unsigned short*)Av;
#pragma unroll
            for (int p = 0; p < 2; ++p) {
                int r = p * 64 + (tid >> 2), seg = tid & 3;
                bf16x8 v = *(const bf16x8*)(A + (size_t)(m0 + r) * DM + k0 + seg * 8);
                *(bf16x8*)(&As[r][seg * 8]) = v;
            }
        }
#pragma unroll
        for (int p = 0; p < 2; ++p) {
            int r = p * 64 + (tid >> 2), seg = tid & 3;
            bf16x8 v = *(const bf16x8*)(Bt + (size_t)(n0 + r) * DM + k0 + seg * 8);
            *(bf16x8*)(&Bs[r][seg * 8]) = v;
        }
        __syncthreads();

        bf16x8 af[4], bfr[4];
#pragma unroll
        for (int mi = 0; mi < 4; ++mi)
            af[mi] = *(const bf16x8*)(&As[wm * 64 + mi * 16 + lc][lg * 8]);
#pragma unroll
        for (int ni = 0; ni < 4; ++ni)
            bfr[ni] = *(const bf16x8*)(&Bs[wn * 64 + ni * 16 + lc][lg * 8]);
#pragma unroll
        for (int mi = 0; mi < 4; ++mi)
#pragma unroll
            for (int ni = 0; ni < 4; ++ni)
                acc[mi][ni] = __builtin_amdgcn_mfma_f32_16x16x32_bf16(af[mi], bfr[ni],
                                                                      acc[mi][ni], 0, 0, 0);
    }

#pragma unroll
    for (int mi = 0; mi < 4; ++mi)
#pragma unroll
        for (int ni = 0; ni < 4; ++ni)
#pragma unroll
            for (int r = 0; r < 4; ++r) {
                int m = m0 + wm * 64 + mi * 16 + lg * 4 + r;
                int n = n0 + wn * 64 + ni * 16 + lc;
                float val = (acc[mi][ni][r] + bias[n]) * scale;
                if (OUT_MODE == 0) {
                    int b = m >> 11, t = m & (TT - 1), h = n >> 6, d = n & 63;
                    ((unsigned short*)Cv)[(((size_t)b * NH + h) * TT + t) * HD + d] = f2bf(val);
                } else {
                    ((float*)Cv)[(size_t)m * DM + n] = val;
                }
            }
}

// ---- flash attention: Q,K,V bf16 [b*NH+h][T][64]; out bf16 [b*T+t][h*64+d] ----
__global__ __launch_bounds__(256) void k_attn(const unsigned short* __restrict__ Qg,
                                              const unsigned short* __restrict__ Kg,
                                              const unsigned short* __restrict__ Vg,
                                              const int* __restrict__ pm,
                                              unsigned short* __restrict__ Og) {
    const int bh = blockIdx.y;
    const int b = bh >> 4, h = bh & 15;
    const int qbase = blockIdx.x * 64;
    const int tid = threadIdx.x;
    const int wid = tid >> 6, lane = tid & 63;
    const int lg = lane >> 4, lc = lane & 15;
    const int qw = qbase + wid * 16;

    const unsigned short* Qh = Qg + (size_t)bh * TT * HD;
    const unsigned short* Kh = Kg + (size_t)bh * TT * HD;
    const unsigned short* Vh = Vg + (size_t)bh * TT * HD;

    // hoist Q fragments (16 q-rows x 64 d per wave)
    const int qrow = qw + lc;
    bf16x8 qf0 = *(const bf16x8*)(Qh + (size_t)qrow * HD + lg * 8);
    bf16x8 qf1 = *(const bf16x8*)(Qh + (size_t)qrow * HD + 32 + lg * 8);

    f32x4 accd[4];
#pragma unroll
    for (int dc = 0; dc < 4; ++dc) accd[dc] = (f32x4){0.f, 0.f, 0.f, 0.f};
    float mrow[4] = {-INFINITY, -INFINITY, -INFINITY, -INFINITY};
    float lrow[4] = {0.f, 0.f, 0.f, 0.f};

    __shared__ __align__(16) unsigned short Vt[64][56];       // Vt[d][k]
    __shared__ __align__(16) unsigned short Pl[4][16][56];    // per-wave P[q][k]

    const int kend = qbase + 64;
    for (int kv0 = 0; kv0 < kend; kv0 += 32) {
        __syncthreads();
        {   // stage V^T tile: Vt[d][kk] = V[kv0+kk][d]
            int kk = tid >> 3, seg = tid & 7;
            bf16x8 v = *(const bf16x8*)(Vh + (size_t)(kv0 + kk) * HD + seg * 8);
#pragma unroll
            for (int j = 0; j < 8; ++j)
                Vt[seg * 8 + j][kk] = (unsigned short)v[j];
        }
        __syncthreads();

        if (kv0 <= qw + 15) {   // wave-uniform causal skip
            // S = Q @ K^T  (two 16-key column tiles)
            const unsigned short* kr0 = Kh + (size_t)(kv0 + lc) * HD;
            const unsigned short* kr1 = Kh + (size_t)(kv0 + 16 + lc) * HD;
            bf16x8 kf00 = *(const bf16x8*)(kr0 + lg * 8);
            bf16x8 kf01 = *(const bf16x8*)(kr0 + 32 + lg * 8);
            bf16x8 kf10 = *(const bf16x8*)(kr1 + lg * 8);
            bf16x8 kf11 = *(const bf16x8*)(kr1 + 32 + lg * 8);
            f32x4 s0 = (f32x4){0.f, 0.f, 0.f, 0.f};
            f32x4 s1 = (f32x4){0.f, 0.f, 0.f, 0.f};
            s0 = __builtin_amdgcn_mfma_f32_16x16x32_bf16(qf0, kf00, s0, 0, 0, 0);
            s0 = __builtin_amdgcn_mfma_f32_16x16x32_bf16(qf1, kf01, s0, 0, 0, 0);
            s1 = __builtin_amdgcn_mfma_f32_16x16x32_bf16(qf0, kf10, s1, 0, 0, 0);
            s1 = __builtin_amdgcn_mfma_f32_16x16x32_bf16(qf1, kf11, s1, 0, 0, 0);

            const int key0 = kv0 + lc, key1 = kv0 + 16 + lc;
            const bool pad0 = (pm[b * TT + key0] == 0);
            const bool pad1 = (pm[b * TT + key1] == 0);

#pragma unroll
            for (int r = 0; r < 4; ++r) {
                int qg = qw + lg * 4 + r;
                float s0v = (key0 > qg || pad0) ? -INFINITY : s0[r];
                float s1v = (key1 > qg || pad1) ? -INFINITY : s1[r];
                float tmax = fmaxf(s0v, s1v);
                tmax = fmaxf(tmax, __shfl_xor(tmax, 1));
                tmax = fmaxf(tmax, __shfl_xor(tmax, 2));
                tmax = fmaxf(tmax, __shfl_xor(tmax, 4));
                tmax = fmaxf(tmax, __shfl_xor(tmax, 8));
                float mnew = fmaxf(mrow[r], tmax);
                float esc = __expf(mrow[r] - mnew);
                float e0 = __expf(s0v - mnew);
                float e1 = __expf(s1v - mnew);
                float ps = e0 + e1;
                ps += __shfl_xor(ps, 1);
                ps += __shfl_xor(ps, 2);
                ps += __shfl_xor(ps, 4);
                ps += __shfl_xor(ps, 8);
                lrow[r] = lrow[r] * esc + ps;
                mrow[r] = mnew;
#pragma unroll
                for (int dc = 0; dc < 4; ++dc) accd[dc][r] *= esc;
                Pl[wid][lg * 4 + r][lc] = f2bf(e0);
                Pl[wid][lg * 4 + r][16 + lc] = f2bf(e1);
            }

            // PV: A = P[16 q][32 k] from per-wave LDS, B = V^T from Vt
            bf16x8 pa = *(const bf16x8*)(&Pl[wid][lc][lg * 8]);
#pragma unroll
            for (int dc = 0; dc < 4; ++dc) {
                bf16x8 vb = *(const bf16x8*)(&Vt[dc * 16 + lc][lg * 8]);
                accd[dc] = __builtin_amdgcn_mfma_f32_16x16x32_bf16(pa, vb, accd[dc], 0, 0, 0);
            }
        }
    }

    // epilogue: normalize, write [b*T+t][h*64+d] bf16
#pragma unroll
    for (int r = 0; r < 4; ++r) {
        float inv = 1.0f / lrow[r];
        int qg = qw + lg * 4 + r;
#pragma unroll
        for (int dc = 0; dc < 4; ++dc) {
            float val = accd[dc][r] * inv;
            Og[((size_t)b * TT + qg) * DM + h * HD + dc * 16 + lc] = f2bf(val);
        }
    }
}

extern "C" void kernel_launch(void* const* d_in, const int* in_sizes, int n_in,
                              void* d_out, int out_size, void* d_ws, size_t ws_size,
                              hipStream_t stream) {
    const float* xq = (const float*)d_in[0];
    const float* xk = (const float*)d_in[1];
    const float* xv = (const float*)d_in[2];
    const int* pmask = (const int*)d_in[3];
    const float* Wq = (const float*)d_in[4];
    const float* bq = (const float*)d_in[5];
    const float* Wk = (const float*)d_in[6];
    const float* bk = (const float*)d_in[7];
    const float* Wv = (const float*)d_in[8];
    const float* bv = (const float*)d_in[9];
    const float* Wo = (const float*)d_in[10];
    const float* bo = (const float*)d_in[11];

    char* ws = (char*)d_ws;
    const size_t WT = (size_t)DM * DM * 2;          // 2 MB per transposed weight
    const size_t QKV = (size_t)NB * NH * TT * HD * 2;  // 16 MB each
    unsigned short* WqT = (unsigned short*)(ws + 0 * WT);
    unsigned short* WkT = (unsigned short*)(ws + 1 * WT);
    unsigned short* WvT = (unsigned short*)(ws + 2 * WT);
    unsigned short* WoT = (unsigned short*)(ws + 3 * WT);
    unsigned short* Qb = (unsigned short*)(ws + 4 * WT);
    unsigned short* Kb = (unsigned short*)(ws + 4 * WT + QKV);
    unsigned short* Vb = (unsigned short*)(ws + 4 * WT + 2 * QKV);
    unsigned short* Ob = (unsigned short*)(ws + 4 * WT + 3 * QKV);

    dim3 tb(32, 8);
    k_transpose_w<<<dim3(32, 32), tb, 0, stream>>>(Wq, WqT);
    k_transpose_w<<<dim3(32, 32), tb, 0, stream>>>(Wk, WkT);
    k_transpose_w<<<dim3(32, 32), tb, 0, stream>>>(Wv, WvT);
    k_transpose_w<<<dim3(32, 32), tb, 0, stream>>>(Wo, WoT);

    dim3 gg(64, 8);  // M/128, N/128
    k_gemm<0, false><<<gg, 256, 0, stream>>>(xq, WqT, bq, Qb, 0.125f);
    k_gemm<0, false><<<gg, 256, 0, stream>>>(xk, WkT, bk, Kb, 1.0f);
    k_gemm<0, false><<<gg, 256, 0, stream>>>(xv, WvT, bv, Vb, 1.0f);

    k_attn<<<dim3(TT / 64, NB * NH), 256, 0, stream>>>(Qb, Kb, Vb, pmask, Ob);

    k_gemm<1, true><<<gg, 256, 0, stream>>>(Ob, WoT, bo, d_out, 1.0f);
}